// Round 7
// baseline (856.857 us; speedup 1.0000x reference)
//
#include <hip/hip_runtime.h>

// Trilinear sampling of tsdf/weights volumes at M = B*H*N points.
// D = 256 fixed (reference). Outputs concatenated flat in d_out as float32:
//   [0,        M)   fusion_values
//   [M,      25M)   indices  (M,8,3) -- stored as float-valued integers
//   [25M,    33M)   weights  (M,8)
//   [33M,    34M)   fusion_weights
//
// v6: v4 brick layout (2x2x2 bricks of (t,w) pairs, 64 B/brick, cheap pack)
//   + TWO points per thread with all 16 gathers issued as one batch.
//   Rationale: v3->v5 cut gather bytes 45% / requests 50% for <5% time --
//   gathers are free at the margin => latency-bound, not traffic-bound.
//   VGPR_Count was only 24-28: the compiler serialized the 8 gathers to
//   ~3-4 in flight. v6 deliberately raises VGPR (~90) to triple in-flight
//   gathers per SIMD (occupancy 80%->~60%, MLP 25->~80 per SIMD).
//   Also: 8 B vector point loads, coalesced 8 B fv/fw stores.

typedef float v2f __attribute__((ext_vector_type(2)));
typedef float v4f __attribute__((ext_vector_type(4)));

// ---------------- pack: 2x2x2 bricks, one thread per brick -----------------
__global__ __launch_bounds__(256) void pack_brick_kernel(
    const float* __restrict__ tsdf,
    const float* __restrict__ wvol,
    float* __restrict__ packed)      // 128^3 bricks * 16 floats
{
    const int t = blockIdx.x * 256 + threadIdx.x;
    const int bz = t & 127;
    const int by = (t >> 7) & 127;
    const int bx = t >> 14;
    const int x0 = bx << 1, y0 = by << 1, z0 = bz << 1;

    v4f o[4];
#pragma unroll
    for (int dx = 0; dx < 2; ++dx) {
#pragma unroll
        for (int dy = 0; dy < 2; ++dy) {
            const size_t src = ((size_t)(x0 + dx) << 16) |
                               (size_t)((y0 + dy) << 8) | (size_t)z0;
            const v2f tp = *reinterpret_cast<const v2f*>(tsdf + src);
            const v2f wp = *reinterpret_cast<const v2f*>(wvol + src);
            v4f o4; o4.x = tp.x; o4.y = wp.x; o4.z = tp.y; o4.w = wp.y;
            o[dx * 2 + dy] = o4;
        }
    }
    v4f* __restrict__ dst = reinterpret_cast<v4f*>(packed + ((size_t)t << 4));
    dst[0] = o[0];
    dst[1] = o[1];
    dst[2] = o[2];
    dst[3] = o[3];
}

// ---------------- v6 extractor: 2 points/thread, 16 batched gathers --------
__global__ __launch_bounds__(256) void extractor2(
    const float* __restrict__ points,
    const float* __restrict__ packed,
    float* __restrict__ out,
    int Mhalf, int M)
{
    const int t = blockIdx.x * 256 + threadIdx.x;
    if (t >= Mhalf) return;

    // two points = 6 floats, 24 B, 8 B-aligned -> three v2f loads
    const float* pp = points + 6ull * (size_t)t;
    const v2f pA = *reinterpret_cast<const v2f*>(pp + 0);
    const v2f pB = *reinterpret_cast<const v2f*>(pp + 2);
    const v2f pC = *reinterpret_cast<const v2f*>(pp + 4);

    const float PX[2] = {pA.x, pB.y};
    const float PY[2] = {pA.y, pC.x};
    const float PZ[2] = {pB.x, pC.y};

    // per-point geometry
    int   BX[2], BY[2], BZ[2], NX[2], NY[2], NZ[2];
    float AX[2], AY[2], AZ[2], AXI[2], AYI[2], AZI[2];
#pragma unroll
    for (int p = 0; p < 2; ++p) {
        const float fx = floorf(PX[p]), fy = floorf(PY[p]), fz = floorf(PZ[p]);
        BX[p] = (int)fx; BY[p] = (int)fy; BZ[p] = (int)fz;
        const float dxc = fx + 0.5f - PX[p];
        const float dyc = fy + 0.5f - PY[p];
        const float dzc = fz + 0.5f - PZ[p];
        NX[p] = (dxc > 0.f) ? 1 : ((dxc < 0.f) ? -1 : 0);
        NY[p] = (dyc > 0.f) ? 1 : ((dyc < 0.f) ? -1 : 0);
        NZ[p] = (dzc > 0.f) ? 1 : ((dzc < 0.f) ? -1 : 0);
        AX[p] = fabsf(dxc); AY[p] = fabsf(dyc); AZ[p] = fabsf(dzc);
        AXI[p] = 1.f - AX[p]; AYI[p] = 1.f - AY[p]; AZI[p] = 1.f - AZ[p];
    }

    // all 16 gather offsets (float index into packed), then 16 batched loads
    size_t FIDX[2][8];
#pragma unroll
    for (int p = 0; p < 2; ++p) {
#pragma unroll
        for (int c = 0; c < 8; ++c) {
            const int ox = (c >> 2) & 1;
            const int oy = (c >> 1) & 1;
            const int oz = c & 1;
            const int cx = BX[p] + (ox ? NX[p] : 0);
            const int cy = BY[p] + (oy ? NY[p] : 0);
            const int cz = BZ[p] + (oz ? NZ[p] : 0);
            const int ccx = min(max(cx, 0), 255);
            const int ccy = min(max(cy, 0), 255);
            const int ccz = min(max(cz, 0), 255);
            const int brick = ((ccx >> 1) << 14) | ((ccy >> 1) << 7) | (ccz >> 1);
            const int off = ((ccx & 1) << 2) | ((ccy & 1) << 1) | (ccz & 1);
            FIDX[p][c] = ((size_t)brick << 4) + (size_t)(off << 1);
        }
    }

    v2f TW[2][8];
#pragma unroll
    for (int p = 0; p < 2; ++p) {
#pragma unroll
        for (int c = 0; c < 8; ++c) {
            TW[p][c] = *reinterpret_cast<const v2f*>(packed + FIDX[p][c]);
        }
    }

    // accumulate + write idx/wts (recompute corners: cheap VALU)
    const size_t Ms = (size_t)M;
    float FV[2], FW[2];
#pragma unroll
    for (int p = 0; p < 2; ++p) {
        float fv = 0.f, fw = 0.f;
        float idxf[24];
        float wts[8];
#pragma unroll
        for (int c = 0; c < 8; ++c) {
            const int ox = (c >> 2) & 1;
            const int oy = (c >> 1) & 1;
            const int oz = c & 1;
            const int cx = BX[p] + (ox ? NX[p] : 0);
            const int cy = BY[p] + (oy ? NY[p] : 0);
            const int cz = BZ[p] + (oz ? NZ[p] : 0);
            const float w = (ox ? AX[p] : AXI[p]) * (oy ? AY[p] : AYI[p]) *
                            (oz ? AZ[p] : AZI[p]);
            const bool valid = ((unsigned)cx < 256u) & ((unsigned)cy < 256u) &
                               ((unsigned)cz < 256u);
            const float vm = valid ? 1.f : 0.f;
            fv += TW[p][c].x * vm * w;
            fw += TW[p][c].y * vm * w;
            idxf[c * 3 + 0] = (float)cx;
            idxf[c * 3 + 1] = (float)cy;
            idxf[c * 3 + 2] = (float)cz;
            wts[c] = w;
        }
        FV[p] = fv; FW[p] = fw;

        const size_t m = 2ull * (size_t)t + (size_t)p;
        float4* __restrict__ oi = reinterpret_cast<float4*>(out + Ms + m * 24);
        const float4* ii = reinterpret_cast<const float4*>(idxf);
#pragma unroll
        for (int i = 0; i < 6; ++i) oi[i] = ii[i];

        float4* __restrict__ ow = reinterpret_cast<float4*>(out + 25 * Ms + m * 8);
        const float4* wi = reinterpret_cast<const float4*>(wts);
        ow[0] = wi[0];
        ow[1] = wi[1];
    }

    // coalesced 8 B stores for fv / fw
    v2f fvv; fvv.x = FV[0]; fvv.y = FV[1];
    v2f fwv; fwv.x = FW[0]; fwv.y = FW[1];
    *reinterpret_cast<v2f*>(out + 2ull * (size_t)t) = fvv;
    *reinterpret_cast<v2f*>(out + 33 * Ms + 2ull * (size_t)t) = fwv;
}

// ---------------- v1 fallback: no workspace ---------------------------------
__global__ __launch_bounds__(256) void extractor_kernel(
    const float* __restrict__ points,
    const float* __restrict__ tsdf,
    const float* __restrict__ wvol,
    float* __restrict__ out,
    int M)
{
    const int m = blockIdx.x * 256 + threadIdx.x;
    if (m >= M) return;

    const size_t p3 = 3ull * (size_t)m;
    const float px = points[p3 + 0];
    const float py = points[p3 + 1];
    const float pz = points[p3 + 2];

    const float fx = floorf(px), fy = floorf(py), fz = floorf(pz);
    const int bx = (int)fx, by = (int)fy, bz = (int)fz;

    const float dxc = fx + 0.5f - px;
    const float dyc = fy + 0.5f - py;
    const float dzc = fz + 0.5f - pz;

    const int nx = (dxc > 0.f) ? 1 : ((dxc < 0.f) ? -1 : 0);
    const int ny = (dyc > 0.f) ? 1 : ((dyc < 0.f) ? -1 : 0);
    const int nz = (dzc > 0.f) ? 1 : ((dzc < 0.f) ? -1 : 0);

    const float ax = fabsf(dxc), ay = fabsf(dyc), az = fabsf(dzc);
    const float axi = 1.f - ax, ayi = 1.f - ay, azi = 1.f - az;

    float fv = 0.f, fw = 0.f;
    float idxf[24];
    float wts[8];

#pragma unroll
    for (int c = 0; c < 8; ++c) {
        const int ox = (c >> 2) & 1;
        const int oy = (c >> 1) & 1;
        const int oz = c & 1;
        const int cx = bx + (ox ? nx : 0);
        const int cy = by + (oy ? ny : 0);
        const int cz = bz + (oz ? nz : 0);
        const float w = (ox ? ax : axi) * (oy ? ay : ayi) * (oz ? az : azi);
        const bool valid = ((unsigned)cx < 256u) & ((unsigned)cy < 256u) & ((unsigned)cz < 256u);
        const int ccx = min(max(cx, 0), 255);
        const int ccy = min(max(cy, 0), 255);
        const int ccz = min(max(cz, 0), 255);
        const int flat = (ccx << 16) | (ccy << 8) | ccz;
        const float vm = valid ? 1.f : 0.f;
        const float tv = tsdf[flat] * vm;
        const float wv = wvol[flat] * vm;
        fv += tv * w;
        fw += wv * w;
        idxf[c * 3 + 0] = (float)cx;
        idxf[c * 3 + 1] = (float)cy;
        idxf[c * 3 + 2] = (float)cz;
        wts[c] = w;
    }

    const size_t Ms = (size_t)M;
    out[m] = fv;
    out[33 * Ms + m] = fw;

    float4* __restrict__ oi = reinterpret_cast<float4*>(out + Ms + (size_t)m * 24);
    const float4* ii = reinterpret_cast<const float4*>(idxf);
#pragma unroll
    for (int i = 0; i < 6; ++i) oi[i] = ii[i];

    float4* __restrict__ ow = reinterpret_cast<float4*>(out + 25 * Ms + (size_t)m * 8);
    const float4* wi = reinterpret_cast<const float4*>(wts);
    ow[0] = wi[0];
    ow[1] = wi[1];
}

extern "C" void kernel_launch(void* const* d_in, const int* in_sizes, int n_in,
                              void* d_out, int out_size, void* d_ws, size_t ws_size,
                              hipStream_t stream) {
    const float* points = (const float*)d_in[0];
    const float* tsdf   = (const float*)d_in[1];
    const float* wvol   = (const float*)d_in[2];
    float* out = (float*)d_out;

    const int M = in_sizes[0] / 3;               // B*H*N
    const size_t need_brick = 134217728ull;      // 128 MiB: 128^3 * 64 B

    if (ws_size >= need_brick && (M % 2) == 0) {
        float* packed = (float*)d_ws;
        const int nbricks = 128 * 128 * 128;
        pack_brick_kernel<<<nbricks / 256, 256, 0, stream>>>(tsdf, wvol, packed);
        const int Mhalf = M / 2;
        const int blocks2 = (Mhalf + 255) / 256;
        extractor2<<<blocks2, 256, 0, stream>>>(points, packed, out, Mhalf, M);
    } else {
        const int blocks = (M + 255) / 256;
        extractor_kernel<<<blocks, 256, 0, stream>>>(points, tsdf, wvol, out, M);
    }
}

// Round 8
// 663.791 us; speedup vs baseline: 1.2909x; 1.2909x over previous
//
#include <hip/hip_runtime.h>

// Trilinear sampling of tsdf/weights volumes at M = B*H*N points.
// D = 256 fixed (reference). Outputs concatenated flat in d_out as float32:
//   [0,        M)   fusion_values
//   [M,      25M)   indices  (M,8,3) -- stored as float-valued integers
//   [25M,    33M)   weights  (M,8)
//   [33M,    34M)   fusion_weights
//
// v7: v4 compute (2x2x2 brick (t,w) layout, 8 gathers/pt, cheap pack) +
//   LDS-transposed FULLY-COALESCED output stores.
//   Evidence: gathers are ~free at the margin (v3->v5: -45% bytes, -50%
//   requests => <5% time), but store-pattern perturbations move time a lot
//   (v2 nt: +14%; v6 192B-stride: +56%, WRITE 2.4x). The invariant ~275us
//   floor is the write path: 16B partial-sector stores at 96B lane stride,
//   4 transactions per 64B line. v7 stages idx (24KB) & wts (8KB, reused
//   buffer) in LDS, then writes lane-contiguous float4 bursts (full lines
//   per instruction). LDS linear (no pad): 24KB -> 6 blocks/CU, ~75% occ.

typedef float v2f __attribute__((ext_vector_type(2)));
typedef float v4f __attribute__((ext_vector_type(4)));

// ---------------- pack: 2x2x2 bricks, one thread per brick -----------------
__global__ __launch_bounds__(256) void pack_brick_kernel(
    const float* __restrict__ tsdf,
    const float* __restrict__ wvol,
    float* __restrict__ packed)      // 128^3 bricks * 16 floats
{
    const int t = blockIdx.x * 256 + threadIdx.x;
    const int bz = t & 127;
    const int by = (t >> 7) & 127;
    const int bx = t >> 14;
    const int x0 = bx << 1, y0 = by << 1, z0 = bz << 1;

    v4f o[4];
#pragma unroll
    for (int dx = 0; dx < 2; ++dx) {
#pragma unroll
        for (int dy = 0; dy < 2; ++dy) {
            const size_t src = ((size_t)(x0 + dx) << 16) |
                               (size_t)((y0 + dy) << 8) | (size_t)z0;
            const v2f tp = *reinterpret_cast<const v2f*>(tsdf + src);
            const v2f wp = *reinterpret_cast<const v2f*>(wvol + src);
            v4f o4; o4.x = tp.x; o4.y = wp.x; o4.z = tp.y; o4.w = wp.y;
            o[dx * 2 + dy] = o4;
        }
    }
    v4f* __restrict__ dst = reinterpret_cast<v4f*>(packed + ((size_t)t << 4));
    dst[0] = o[0];
    dst[1] = o[1];
    dst[2] = o[2];
    dst[3] = o[3];
}

// ---------------- v7 extractor: v4 compute + LDS-coalesced stores ----------
// Requires M % 256 == 0 (host checks; true for the reference shape).
__global__ __launch_bounds__(256) void extractor_lds(
    const float* __restrict__ points,
    const float* __restrict__ packed,
    float* __restrict__ out,
    int M)
{
    __shared__ v4f s4[256 * 6];      // 24 KB; idx phase uses 1536, wts 512

    const int tid = threadIdx.x;
    const int m = blockIdx.x * 256 + tid;

    const size_t p3 = 3ull * (size_t)m;
    const float px = points[p3 + 0];
    const float py = points[p3 + 1];
    const float pz = points[p3 + 2];

    const float fx = floorf(px), fy = floorf(py), fz = floorf(pz);
    const int bx = (int)fx, by = (int)fy, bz = (int)fz;

    const float dxc = fx + 0.5f - px;
    const float dyc = fy + 0.5f - py;
    const float dzc = fz + 0.5f - pz;

    const int nx = (dxc > 0.f) ? 1 : ((dxc < 0.f) ? -1 : 0);
    const int ny = (dyc > 0.f) ? 1 : ((dyc < 0.f) ? -1 : 0);
    const int nz = (dzc > 0.f) ? 1 : ((dzc < 0.f) ? -1 : 0);

    const float ax = fabsf(dxc), ay = fabsf(dyc), az = fabsf(dzc);
    const float axi = 1.f - ax, ayi = 1.f - ay, azi = 1.f - az;

    float fv = 0.f, fw = 0.f;
    float idxf[24];
    float wts[8];

#pragma unroll
    for (int c = 0; c < 8; ++c) {
        const int ox = (c >> 2) & 1;
        const int oy = (c >> 1) & 1;
        const int oz = c & 1;
        const int cx = bx + (ox ? nx : 0);
        const int cy = by + (oy ? ny : 0);
        const int cz = bz + (oz ? nz : 0);
        const float w = (ox ? ax : axi) * (oy ? ay : ayi) * (oz ? az : azi);
        const bool valid = ((unsigned)cx < 256u) & ((unsigned)cy < 256u) & ((unsigned)cz < 256u);
        const int ccx = min(max(cx, 0), 255);
        const int ccy = min(max(cy, 0), 255);
        const int ccz = min(max(cz, 0), 255);
        const int brick = ((ccx >> 1) << 14) | ((ccy >> 1) << 7) | (ccz >> 1);
        const int off = ((ccx & 1) << 2) | ((ccy & 1) << 1) | (ccz & 1);
        const size_t fidx = ((size_t)brick << 4) + (size_t)(off << 1);
        const float vm = valid ? 1.f : 0.f;
        const v2f tw = *reinterpret_cast<const v2f*>(packed + fidx);
        fv += tw.x * vm * w;
        fw += tw.y * vm * w;
        idxf[c * 3 + 0] = (float)cx;
        idxf[c * 3 + 1] = (float)cy;
        idxf[c * 3 + 2] = (float)cz;
        wts[c] = w;
    }

    const size_t Ms = (size_t)M;
    // fv / fw: already lane-contiguous scalar stores
    out[m] = fv;
    out[33 * Ms + m] = fw;

    // ---- idx: stage per-thread 6 float4s, then write lane-contiguous ----
    const v4f* ii = reinterpret_cast<const v4f*>(idxf);
#pragma unroll
    for (int k = 0; k < 6; ++k) s4[tid * 6 + k] = ii[k];
    __syncthreads();
    v4f* __restrict__ dsti =
        reinterpret_cast<v4f*>(out + Ms + (size_t)blockIdx.x * 6144);
#pragma unroll
    for (int k = 0; k < 6; ++k) dsti[k * 256 + tid] = s4[k * 256 + tid];
    __syncthreads();

    // ---- wts: same trick, reusing the buffer ----
    const v4f* wi = reinterpret_cast<const v4f*>(wts);
    s4[tid * 2 + 0] = wi[0];
    s4[tid * 2 + 1] = wi[1];
    __syncthreads();
    v4f* __restrict__ dstw =
        reinterpret_cast<v4f*>(out + 25 * Ms + (size_t)blockIdx.x * 2048);
    dstw[0 * 256 + tid] = s4[0 * 256 + tid];
    dstw[1 * 256 + tid] = s4[1 * 256 + tid];
}

// ---------------- v4 extractor (fallback when M % 256 != 0) ---------------
__global__ __launch_bounds__(256) void extractor_packed(
    const float* __restrict__ points,
    const float* __restrict__ packed,
    float* __restrict__ out,
    int M)
{
    const int m = blockIdx.x * 256 + threadIdx.x;
    if (m >= M) return;

    const size_t p3 = 3ull * (size_t)m;
    const float px = points[p3 + 0];
    const float py = points[p3 + 1];
    const float pz = points[p3 + 2];

    const float fx = floorf(px), fy = floorf(py), fz = floorf(pz);
    const int bx = (int)fx, by = (int)fy, bz = (int)fz;

    const float dxc = fx + 0.5f - px;
    const float dyc = fy + 0.5f - py;
    const float dzc = fz + 0.5f - pz;

    const int nx = (dxc > 0.f) ? 1 : ((dxc < 0.f) ? -1 : 0);
    const int ny = (dyc > 0.f) ? 1 : ((dyc < 0.f) ? -1 : 0);
    const int nz = (dzc > 0.f) ? 1 : ((dzc < 0.f) ? -1 : 0);

    const float ax = fabsf(dxc), ay = fabsf(dyc), az = fabsf(dzc);
    const float axi = 1.f - ax, ayi = 1.f - ay, azi = 1.f - az;

    float fv = 0.f, fw = 0.f;
    float idxf[24];
    float wts[8];

#pragma unroll
    for (int c = 0; c < 8; ++c) {
        const int ox = (c >> 2) & 1;
        const int oy = (c >> 1) & 1;
        const int oz = c & 1;
        const int cx = bx + (ox ? nx : 0);
        const int cy = by + (oy ? ny : 0);
        const int cz = bz + (oz ? nz : 0);
        const float w = (ox ? ax : axi) * (oy ? ay : ayi) * (oz ? az : azi);
        const bool valid = ((unsigned)cx < 256u) & ((unsigned)cy < 256u) & ((unsigned)cz < 256u);
        const int ccx = min(max(cx, 0), 255);
        const int ccy = min(max(cy, 0), 255);
        const int ccz = min(max(cz, 0), 255);
        const int brick = ((ccx >> 1) << 14) | ((ccy >> 1) << 7) | (ccz >> 1);
        const int off = ((ccx & 1) << 2) | ((ccy & 1) << 1) | (ccz & 1);
        const size_t fidx = ((size_t)brick << 4) + (size_t)(off << 1);
        const float vm = valid ? 1.f : 0.f;
        const v2f tw = *reinterpret_cast<const v2f*>(packed + fidx);
        fv += tw.x * vm * w;
        fw += tw.y * vm * w;
        idxf[c * 3 + 0] = (float)cx;
        idxf[c * 3 + 1] = (float)cy;
        idxf[c * 3 + 2] = (float)cz;
        wts[c] = w;
    }

    const size_t Ms = (size_t)M;
    out[m] = fv;
    out[33 * Ms + m] = fw;

    float4* __restrict__ oi = reinterpret_cast<float4*>(out + Ms + (size_t)m * 24);
    const float4* ii = reinterpret_cast<const float4*>(idxf);
#pragma unroll
    for (int i = 0; i < 6; ++i) oi[i] = ii[i];

    float4* __restrict__ ow = reinterpret_cast<float4*>(out + 25 * Ms + (size_t)m * 8);
    const float4* wi = reinterpret_cast<const float4*>(wts);
    ow[0] = wi[0];
    ow[1] = wi[1];
}

// ---------------- v1 fallback: no workspace ---------------------------------
__global__ __launch_bounds__(256) void extractor_kernel(
    const float* __restrict__ points,
    const float* __restrict__ tsdf,
    const float* __restrict__ wvol,
    float* __restrict__ out,
    int M)
{
    const int m = blockIdx.x * 256 + threadIdx.x;
    if (m >= M) return;

    const size_t p3 = 3ull * (size_t)m;
    const float px = points[p3 + 0];
    const float py = points[p3 + 1];
    const float pz = points[p3 + 2];

    const float fx = floorf(px), fy = floorf(py), fz = floorf(pz);
    const int bx = (int)fx, by = (int)fy, bz = (int)fz;

    const float dxc = fx + 0.5f - px;
    const float dyc = fy + 0.5f - py;
    const float dzc = fz + 0.5f - pz;

    const int nx = (dxc > 0.f) ? 1 : ((dxc < 0.f) ? -1 : 0);
    const int ny = (dyc > 0.f) ? 1 : ((dyc < 0.f) ? -1 : 0);
    const int nz = (dzc > 0.f) ? 1 : ((dzc < 0.f) ? -1 : 0);

    const float ax = fabsf(dxc), ay = fabsf(dyc), az = fabsf(dzc);
    const float axi = 1.f - ax, ayi = 1.f - ay, azi = 1.f - az;

    float fv = 0.f, fw = 0.f;
    float idxf[24];
    float wts[8];

#pragma unroll
    for (int c = 0; c < 8; ++c) {
        const int ox = (c >> 2) & 1;
        const int oy = (c >> 1) & 1;
        const int oz = c & 1;
        const int cx = bx + (ox ? nx : 0);
        const int cy = by + (oy ? ny : 0);
        const int cz = bz + (oz ? nz : 0);
        const float w = (ox ? ax : axi) * (oy ? ay : ayi) * (oz ? az : azi);
        const bool valid = ((unsigned)cx < 256u) & ((unsigned)cy < 256u) & ((unsigned)cz < 256u);
        const int ccx = min(max(cx, 0), 255);
        const int ccy = min(max(cy, 0), 255);
        const int ccz = min(max(cz, 0), 255);
        const int flat = (ccx << 16) | (ccy << 8) | ccz;
        const float vm = valid ? 1.f : 0.f;
        const float tv = tsdf[flat] * vm;
        const float wv = wvol[flat] * vm;
        fv += tv * w;
        fw += wv * w;
        idxf[c * 3 + 0] = (float)cx;
        idxf[c * 3 + 1] = (float)cy;
        idxf[c * 3 + 2] = (float)cz;
        wts[c] = w;
    }

    const size_t Ms = (size_t)M;
    out[m] = fv;
    out[33 * Ms + m] = fw;

    float4* __restrict__ oi = reinterpret_cast<float4*>(out + Ms + (size_t)m * 24);
    const float4* ii = reinterpret_cast<const float4*>(idxf);
#pragma unroll
    for (int i = 0; i < 6; ++i) oi[i] = ii[i];

    float4* __restrict__ ow = reinterpret_cast<float4*>(out + 25 * Ms + (size_t)m * 8);
    const float4* wi = reinterpret_cast<const float4*>(wts);
    ow[0] = wi[0];
    ow[1] = wi[1];
}

extern "C" void kernel_launch(void* const* d_in, const int* in_sizes, int n_in,
                              void* d_out, int out_size, void* d_ws, size_t ws_size,
                              hipStream_t stream) {
    const float* points = (const float*)d_in[0];
    const float* tsdf   = (const float*)d_in[1];
    const float* wvol   = (const float*)d_in[2];
    float* out = (float*)d_out;

    const int M = in_sizes[0] / 3;               // B*H*N
    const size_t need_brick = 134217728ull;      // 128 MiB: 128^3 * 64 B

    if (ws_size >= need_brick) {
        float* packed = (float*)d_ws;
        const int nbricks = 128 * 128 * 128;
        pack_brick_kernel<<<nbricks / 256, 256, 0, stream>>>(tsdf, wvol, packed);
        if ((M % 256) == 0) {
            extractor_lds<<<M / 256, 256, 0, stream>>>(points, packed, out, M);
        } else {
            const int blocks = (M + 255) / 256;
            extractor_packed<<<blocks, 256, 0, stream>>>(points, packed, out, M);
        }
    } else {
        const int blocks = (M + 255) / 256;
        extractor_kernel<<<blocks, 256, 0, stream>>>(points, tsdf, wvol, out, M);
    }
}